// Round 3
// baseline (3154.526 us; speedup 1.0000x reference)
//
#include <hip/hip_runtime.h>
#include <stdint.h>

// ---- variant switches (iterated across rounds) ----
// BITS_SCHEME: 0 = legacy split-half threefry
//              1 = partitionable, out0 (hi word)        [R1: FAILED, absmax 4.875]
//              2 = partitionable, out1 (lo word)        [R2: FAILED, absmax 5.125]
//              3 = partitionable, out0 ^ out1           [R3: testing]
#define BITS_SCHEME 3
#define LOG_FMA 0       // 0 = plain mul+add (XLA fast-math off); 1 = greedy fma contraction

static constexpr uint32_t BB = 32;
static constexpr uint32_t NN = 524288;      // 2^19
static constexpr uint32_t KK = 52429;       // max(1, round(0.1*N))
static constexpr uint32_t TOT = BB * NN;    // 2^24
static constexpr uint32_t HALFT = TOT / 2;  // 2^23
static constexpr uint32_t EQCAP = 4096;
static constexpr uint32_t HISTBINS = 65536;
static constexpr size_t HISTBYTES = (size_t)BB * HISTBINS * 4u;  // 8 MB

// ---------------- XLA CPU f32 log (Cephes/Eigen-3.3 copy, GenerateVF32Log) ----------------
__device__ __forceinline__ float xla_logf(float xin) {
#pragma clang fp contract(off)
  float x = fmaxf(xin, __uint_as_float(0x00800000u));  // clamp to min normal
  uint32_t bits = __float_as_uint(x);
  float e = (float)((int)(bits >> 23) - 126);          // exponent + 1
  x = __uint_as_float((bits & 0x807fffffu) | 0x3f000000u);  // mantissa in [0.5,1)
  bool mlt = x < 0.707106781186547524f;
  float tmp = mlt ? x : 0.0f;
  x = x - 1.0f;
  e = e - (mlt ? 1.0f : 0.0f);
  x = x + tmp;
  float x2 = x * x;
  float x3 = x2 * x;
  float y, y1, y2;
#if LOG_FMA
  y  = __builtin_fmaf(7.0376836292E-2f, x, -1.1514610310E-1f);
  y1 = __builtin_fmaf(-1.2420140846E-1f, x, 1.4249322787E-1f);
  y2 = __builtin_fmaf(2.0000714765E-1f, x, -2.4999993993E-1f);
  y  = __builtin_fmaf(y, x, 1.1676998740E-1f);
  y1 = __builtin_fmaf(y1, x, -1.6668057665E-1f);
  y2 = __builtin_fmaf(y2, x, 3.3333331174E-1f);
  y  = __builtin_fmaf(y, x3, y1);
  y  = __builtin_fmaf(y, x3, y2);
  y  = y * x3;
  y = __builtin_fmaf(-2.12194440e-4f, e, y);
  x = __builtin_fmaf(-0.5f, x2, x);
  x = x + y;
  x = __builtin_fmaf(0.693359375f, e, x);
  return x;
#else
  y  = 7.0376836292E-2f * x + -1.1514610310E-1f;
  y1 = -1.2420140846E-1f * x + 1.4249322787E-1f;
  y2 = 2.0000714765E-1f * x + -2.4999993993E-1f;
  y  = y * x + 1.1676998740E-1f;
  y1 = y1 * x + -1.6668057665E-1f;
  y2 = y2 * x + 3.3333331174E-1f;
  y  = y * x3 + y1;
  y  = y * x3 + y2;
  y  = y * x3;
  y1 = e * -2.12194440e-4f;
  tmp = x2 * 0.5f;
  y = y + y1;
  x = x - tmp;
  y2 = e * 0.693359375f;
  x = x + y;
  x = x + y2;
  return x;
#endif
}

__device__ __forceinline__ float c_top_val()  { return xla_logf((float)((1.0 - 0.1) / 52429.0)); }
__device__ __forceinline__ float c_rand_val() { return xla_logf((float)(0.1 / 471859.0)); }

// ---------------- threefry-2x32, key = (0, 42) ----------------
__device__ __forceinline__ uint32_t tf_bits(uint32_t i) {
  const uint32_t ks0 = 0u, ks1 = 42u, ks2 = 0x1BD11BDAu ^ 42u;
#if BITS_SCHEME == 0
  uint32_t lo = (i < HALFT) ? i : (i - HALFT);
  uint32_t x0 = lo + ks0;
  uint32_t x1 = (lo + HALFT) + ks1;
#else
  uint32_t x0 = 0u + ks0;   // counts >> 32 == 0 for i < 2^32
  uint32_t x1 = i + ks1;    // low word of 64-bit iota
#endif
#define TFR(r) { x0 += x1; x1 = (x1 << (r)) | (x1 >> (32 - (r))); x1 ^= x0; }
  TFR(13) TFR(15) TFR(26) TFR(6)
  x0 += ks1; x1 += ks2 + 1u;
  TFR(17) TFR(29) TFR(16) TFR(24)
  x0 += ks2; x1 += ks0 + 2u;
  TFR(13) TFR(15) TFR(26) TFR(6)
  x0 += ks0; x1 += ks1 + 3u;
  TFR(17) TFR(29) TFR(16) TFR(24)
  x0 += ks1; x1 += ks2 + 4u;
  TFR(13) TFR(15) TFR(26) TFR(6)
  x0 += ks2; x1 += ks0 + 5u;
#undef TFR
#if BITS_SCHEME == 0
  return (i < HALFT) ? x0 : x1;
#elif BITS_SCHEME == 1
  return x0;        // out0 (hi word)
#elif BITS_SCHEME == 2
  return x1;        // out1 (lo word)
#else
  return x0 ^ x1;   // fold both output words for sub-64-bit widths
#endif
}

__device__ __forceinline__ float gumbel_at(uint32_t i) {
  uint32_t b = tf_bits(i);
  float u = __uint_as_float((b >> 9) | 0x3f800000u) - 1.0f;
  u = fmaxf(u, 1.17549435e-38f);   // exact equiv of u*(1-tiny)+tiny then max(tiny,.)
  float nl = -xla_logf(u);
  return -xla_logf(nl);
}

// monotone key maps
__device__ __forceinline__ uint32_t key_x(float v) { return __float_as_uint(v) & 0x7fffffffu; }
__device__ __forceinline__ uint32_t key_s(float v) {
  uint32_t b = __float_as_uint(v);
  return (b & 0x80000000u) ? ~b : (b | 0x80000000u);
}

// state layout per row (8 x u32): [0]=b_hi [1]=cnt_gt_hi [2]=thr [3]=cnt_gt [4]=m [5]=eq_cnt
__global__ void __launch_bounds__(256)
k_hist(const float* __restrict__ xin, const float* __restrict__ sbuf,
       uint32_t* __restrict__ hist, const uint32_t* __restrict__ st, int src, int pass) {
  uint32_t stride = gridDim.x * blockDim.x;
  for (uint32_t i = blockIdx.x * blockDim.x + threadIdx.x; i < TOT; i += stride) {
    uint32_t row = i >> 19;
    uint32_t key = (src == 0) ? key_x(xin[i]) : key_s(sbuf[i]);
    if (pass == 0) {
      atomicAdd(&hist[row * HISTBINS + (key >> 16)], 1u);
    } else {
      if ((key >> 16) == st[row * 8 + 0])
        atomicAdd(&hist[row * HISTBINS + (key & 0xffffu)], 1u);
    }
  }
}

__global__ void __launch_bounds__(256)
k_scan(const uint32_t* __restrict__ hist, uint32_t* __restrict__ st, int pass) {
  __shared__ uint32_t csum[256];
  int row = blockIdx.x;
  const uint32_t* h = hist + (size_t)row * HISTBINS;
  uint32_t* S = st + row * 8;
  uint32_t kk = (pass == 0) ? KK : (KK - S[1]);
  int t = threadIdx.x;
  uint32_t s = 0;
  for (int j = 0; j < 256; ++j) s += h[t * 256 + j];
  csum[t] = s;
  __syncthreads();
  if (t == 0) {
    uint32_t acc = 0; int bin = 0;
    for (int c = 255; c >= 0; --c) {
      if (acc + csum[c] >= kk) {
        for (int b2 = c * 256 + 255; b2 >= c * 256; --b2) {
          uint32_t hv = h[b2];
          if (acc + hv >= kk) { bin = b2; break; }
          acc += hv;
        }
        break;
      }
      acc += csum[c];
    }
    if (pass == 0) { S[0] = (uint32_t)bin; S[1] = acc; }
    else {
      S[2] = (S[0] << 16) | (uint32_t)bin;
      S[3] = S[1] + acc;          // strict-greater count
      S[4] = KK - S[3];           // equals to take (>=1)
      S[5] = 0u;                  // reset eq counter
    }
  }
}

__global__ void __launch_bounds__(256)
k_collect(const float* __restrict__ xin, const float* __restrict__ sbuf,
          uint32_t* __restrict__ st, uint32_t* __restrict__ eq, int src) {
  uint32_t stride = gridDim.x * blockDim.x;
  for (uint32_t i = blockIdx.x * blockDim.x + threadIdx.x; i < TOT; i += stride) {
    uint32_t row = i >> 19;
    uint32_t key = (src == 0) ? key_x(xin[i]) : key_s(sbuf[i]);
    if (key == st[row * 8 + 2]) {
      uint32_t idx = atomicAdd(&st[row * 8 + 5], 1u);
      if (idx < EQCAP) eq[row * EQCAP + idx] = i & (NN - 1u);
    }
  }
}

__global__ void __launch_bounds__(256)
k_choose(uint32_t* __restrict__ st, const uint32_t* __restrict__ eq, uint32_t* __restrict__ sel) {
  int row = blockIdx.x;
  uint32_t* S = st + row * 8;
  uint32_t cnt = S[5]; if (cnt > EQCAP) cnt = EQCAP;
  uint32_t m = S[4];
  for (uint32_t a = threadIdx.x; a < cnt; a += blockDim.x) {
    uint32_t my = eq[row * EQCAP + a];
    uint32_t rank = 0;
    for (uint32_t b2 = 0; b2 < cnt; ++b2) rank += (eq[row * EQCAP + b2] < my) ? 1u : 0u;
    if (rank < m) sel[row * EQCAP + rank] = my;   // lowest-index ties win (lax.top_k stable)
  }
  __syncthreads();
  if (threadIdx.x == 0 && m > cnt) S[4] = cnt;
}

__global__ void __launch_bounds__(256)
k_compute_s(const float* __restrict__ xin, float* __restrict__ sbuf,
            const uint32_t* __restrict__ st1) {
  uint32_t stride = gridDim.x * blockDim.x;
  float CT = c_top_val(), CR = c_rand_val();
  for (uint32_t i = blockIdx.x * blockDim.x + threadIdx.x; i < TOT; i += stride) {
    uint32_t row = i >> 19;
    float c = (key_x(xin[i]) > st1[row * 8 + 2]) ? CT : CR;
    sbuf[i] = c + gumbel_at(i);
  }
}

__global__ void __launch_bounds__(256)
k_fixup_s(float* __restrict__ sbuf, const uint32_t* __restrict__ st1,
          const uint32_t* __restrict__ sel1) {
  int row = blockIdx.x;
  float CT = c_top_val();
  uint32_t m = st1[row * 8 + 4];
  for (uint32_t j = threadIdx.x; j < m; j += blockDim.x) {
    uint32_t i = (uint32_t)row * NN + sel1[row * EQCAP + j];
    sbuf[i] = CT + gumbel_at(i);   // boundary-tie element chosen into topk set
  }
}

__global__ void __launch_bounds__(256)
k_final(const float* __restrict__ xin, float* __restrict__ outp,
        const uint32_t* __restrict__ st2) {
  uint32_t stride = gridDim.x * blockDim.x;
  for (uint32_t i = blockIdx.x * blockDim.x + threadIdx.x; i < TOT; i += stride) {
    uint32_t row = i >> 19;
    uint32_t key = key_s(outp[i]);
    float xv = xin[i];
    outp[i] = (key > st2[row * 8 + 2]) ? xv : 0.0f;
  }
}

__global__ void __launch_bounds__(256)
k_fixup_out(const float* __restrict__ xin, float* __restrict__ outp,
            const uint32_t* __restrict__ st2, const uint32_t* __restrict__ sel2) {
  int row = blockIdx.x;
  uint32_t m = st2[row * 8 + 4];
  for (uint32_t j = threadIdx.x; j < m; j += blockDim.x) {
    uint32_t c = sel2[row * EQCAP + j];
    outp[(uint32_t)row * NN + c] = xin[(uint32_t)row * NN + c];
  }
}

extern "C" void kernel_launch(void* const* d_in, const int* in_sizes, int n_in,
                              void* d_out, int out_size, void* d_ws, size_t ws_size,
                              hipStream_t stream) {
  const float* x = (const float*)d_in[0];
  float* out = (float*)d_out;

  uint8_t* w = (uint8_t*)d_ws;
  uint32_t* hist = (uint32_t*)w;                        // 8 MB
  uint32_t* st1  = (uint32_t*)(w + HISTBYTES);          // 32*8 u32
  uint32_t* st2  = st1 + BB * 8;
  uint32_t* eq1  = st2 + BB * 8;                        // 32*4096 u32 each
  uint32_t* sel1 = eq1 + BB * EQCAP;
  uint32_t* eq2  = sel1 + BB * EQCAP;
  uint32_t* sel2 = eq2 + BB * EQCAP;

  dim3 blk(256), gridF(4096), gridR(BB);

  // ---- stage 1: top-k of |x| ----
  hipMemsetAsync(hist, 0, HISTBYTES, stream);
  k_hist<<<gridF, blk, 0, stream>>>(x, nullptr, hist, st1, 0, 0);
  k_scan<<<gridR, blk, 0, stream>>>(hist, st1, 0);
  hipMemsetAsync(hist, 0, HISTBYTES, stream);
  k_hist<<<gridF, blk, 0, stream>>>(x, nullptr, hist, st1, 0, 1);
  k_scan<<<gridR, blk, 0, stream>>>(hist, st1, 1);
  k_collect<<<gridF, blk, 0, stream>>>(x, nullptr, st1, eq1, 0);
  k_choose<<<gridR, blk, 0, stream>>>(st1, eq1, sel1);

  // ---- s = log(probs) + gumbel  (written into d_out as scratch) ----
  k_compute_s<<<gridF, blk, 0, stream>>>(x, out, st1);
  k_fixup_s<<<gridR, blk, 0, stream>>>(out, st1, sel1);

  // ---- stage 2: top-k of s ----
  hipMemsetAsync(hist, 0, HISTBYTES, stream);
  k_hist<<<gridF, blk, 0, stream>>>(x, out, hist, st2, 1, 0);
  k_scan<<<gridR, blk, 0, stream>>>(hist, st2, 0);
  hipMemsetAsync(hist, 0, HISTBYTES, stream);
  k_hist<<<gridF, blk, 0, stream>>>(x, out, hist, st2, 1, 1);
  k_scan<<<gridR, blk, 0, stream>>>(hist, st2, 1);
  k_collect<<<gridF, blk, 0, stream>>>(x, out, st2, eq2, 1);
  k_choose<<<gridR, blk, 0, stream>>>(st2, eq2, sel2);

  // ---- apply mask ----
  k_final<<<gridF, blk, 0, stream>>>(x, out, st2);
  k_fixup_out<<<gridR, blk, 0, stream>>>(x, out, st2, sel2);
}

// Round 4
// 279.246 us; speedup vs baseline: 11.2966x; 11.2966x over previous
//
#include <hip/hip_runtime.h>
#include <stdint.h>

// ---- frozen correctness variants (validated R3: absmax 0.0) ----
// BITS_SCHEME 3: partitionable threefry, bits = out0 ^ out1
// LOG: Cephes/Eigen no-FMA (XLA CPU), contract off

static constexpr uint32_t BB = 32;
static constexpr uint32_t NN = 524288;      // 2^19
static constexpr uint32_t KK = 52429;       // max(1, round(0.1*N))
static constexpr uint32_t EQCAP = 4096;
static constexpr uint32_t W = 64;           // workgroups per row
static constexpr uint32_t CHUNK = NN / W;   // 8192 elements per WG
static constexpr uint32_t HSLOT = 32 * 2048;          // u32 per hist slot
static constexpr size_t   MEMSET_BYTES = (size_t)(6 * HSLOT + 2 * 32 * 8) * 4u;

// ---------------- XLA CPU f32 log (Cephes/Eigen-3.3, no FMA) ----------------
__device__ __forceinline__ float xla_logf(float xin) {
#pragma clang fp contract(off)
  float x = fmaxf(xin, __uint_as_float(0x00800000u));
  uint32_t bits = __float_as_uint(x);
  float e = (float)((int)(bits >> 23) - 126);
  x = __uint_as_float((bits & 0x807fffffu) | 0x3f000000u);
  bool mlt = x < 0.707106781186547524f;
  float tmp = mlt ? x : 0.0f;
  x = x - 1.0f;
  e = e - (mlt ? 1.0f : 0.0f);
  x = x + tmp;
  float x2 = x * x;
  float x3 = x2 * x;
  float y, y1, y2;
  y  = 7.0376836292E-2f * x + -1.1514610310E-1f;
  y1 = -1.2420140846E-1f * x + 1.4249322787E-1f;
  y2 = 2.0000714765E-1f * x + -2.4999993993E-1f;
  y  = y * x + 1.1676998740E-1f;
  y1 = y1 * x + -1.6668057665E-1f;
  y2 = y2 * x + 3.3333331174E-1f;
  y  = y * x3 + y1;
  y  = y * x3 + y2;
  y  = y * x3;
  y1 = e * -2.12194440e-4f;
  tmp = x2 * 0.5f;
  y = y + y1;
  x = x - tmp;
  y2 = e * 0.693359375f;
  x = x + y;
  x = x + y2;
  return x;
}

__device__ __forceinline__ float c_top_val()  { return xla_logf((float)((1.0 - 0.1) / 52429.0)); }
__device__ __forceinline__ float c_rand_val() { return xla_logf((float)(0.1 / 471859.0)); }

// ---------------- threefry-2x32, key = (0, 42), out0^out1 ----------------
__device__ __forceinline__ uint32_t tf_bits(uint32_t i) {
  const uint32_t ks0 = 0u, ks1 = 42u, ks2 = 0x1BD11BDAu ^ 42u;
  uint32_t x0 = 0u + ks0;
  uint32_t x1 = i + ks1;
#define TFR(r) { x0 += x1; x1 = (x1 << (r)) | (x1 >> (32 - (r))); x1 ^= x0; }
  TFR(13) TFR(15) TFR(26) TFR(6)
  x0 += ks1; x1 += ks2 + 1u;
  TFR(17) TFR(29) TFR(16) TFR(24)
  x0 += ks2; x1 += ks0 + 2u;
  TFR(13) TFR(15) TFR(26) TFR(6)
  x0 += ks0; x1 += ks1 + 3u;
  TFR(17) TFR(29) TFR(16) TFR(24)
  x0 += ks1; x1 += ks2 + 4u;
  TFR(13) TFR(15) TFR(26) TFR(6)
  x0 += ks2; x1 += ks0 + 5u;
#undef TFR
  return x0 ^ x1;
}

__device__ __forceinline__ float gumbel_at(uint32_t i) {
  uint32_t b = tf_bits(i);
  float u = __uint_as_float((b >> 9) | 0x3f800000u) - 1.0f;
  u = fmaxf(u, 1.17549435e-38f);
  float nl = -xla_logf(u);
  return -xla_logf(nl);
}

// monotone key maps
__device__ __forceinline__ uint32_t key_x(float v) { return __float_as_uint(v) & 0x7fffffffu; }
__device__ __forceinline__ uint32_t key_s(float v) {
  uint32_t b = __float_as_uint(v);
  return (b & 0x80000000u) ? ~b : (b | 0x80000000u);
}

// per-row state (8 x u32): [0]=prefix [1]=cnt_gt [2]=thr [4]=m [5]=eq_cnt
// radix passes: p0 bits[31:21] (2048 bins), p1 bits[20:10] (2048), p2 bits[9:0] (1024)

template <int SRC>
__global__ void __launch_bounds__(256)
k_hist(const float* __restrict__ src, uint32_t* __restrict__ hist,
       const uint32_t* __restrict__ st, int pass) {
  __shared__ uint32_t lh[2048];
  uint32_t row = blockIdx.y;
  uint32_t nbins = (pass == 2) ? 1024u : 2048u;
  for (uint32_t b = threadIdx.x; b < nbins; b += 256) lh[b] = 0u;
  __syncthreads();
  uint32_t prefix = st[row * 8 + 0];
  const float4* p = (const float4*)(src + (size_t)row * NN + (size_t)blockIdx.x * CHUNK);
  for (uint32_t j = threadIdx.x; j < CHUNK / 4; j += 256) {
    float4 v = p[j];
    float vv[4] = {v.x, v.y, v.z, v.w};
#pragma unroll
    for (int e = 0; e < 4; ++e) {
      uint32_t key = (SRC == 0) ? key_x(vv[e]) : key_s(vv[e]);
      if (pass == 0) {
        atomicAdd(&lh[key >> 21], 1u);
      } else if (pass == 1) {
        if ((key >> 21) == prefix) atomicAdd(&lh[(key >> 10) & 2047u], 1u);
      } else {
        if ((key >> 10) == prefix) atomicAdd(&lh[key & 1023u], 1u);
      }
    }
  }
  __syncthreads();
  uint32_t* gh = hist + row * 2048;
  for (uint32_t b = threadIdx.x; b < nbins; b += 256) {
    uint32_t v = lh[b];
    if (v) atomicAdd(&gh[b], v);
  }
}

__global__ void __launch_bounds__(256)
k_scan(const uint32_t* __restrict__ hist, uint32_t* __restrict__ st, int pass) {
  __shared__ uint32_t csum[256];
  int row = blockIdx.x;
  uint32_t nbins = (pass == 2) ? 1024u : 2048u;
  uint32_t bpt = nbins >> 8;
  const uint32_t* h = hist + row * 2048;
  uint32_t* S = st + row * 8;
  uint32_t kk = KK - S[1];
  int t = threadIdx.x;
  uint32_t s = 0;
  for (uint32_t j = 0; j < bpt; ++j) s += h[t * bpt + j];
  csum[t] = s;
  __syncthreads();
  if (t == 0) {
    uint32_t acc = 0, bin = 0;
    for (int c = 255; c >= 0; --c) {
      if (acc + csum[c] >= kk) {
        for (int b2 = (c + 1) * (int)bpt - 1; b2 >= c * (int)bpt; --b2) {
          uint32_t hv = h[b2];
          if (acc + hv >= kk) { bin = (uint32_t)b2; break; }
          acc += hv;
        }
        break;
      }
      acc += csum[c];
    }
    uint32_t nb = (pass == 2) ? 10u : 11u;
    uint32_t prefix_new = (S[0] << nb) | bin;
    uint32_t cnt = S[1] + acc;
    if (pass < 2) { S[0] = prefix_new; S[1] = cnt; }
    else { S[2] = prefix_new; S[1] = cnt; S[4] = KK - cnt; S[5] = 0u; }
  }
}

template <int SRC>
__global__ void __launch_bounds__(256)
k_collect(const float* __restrict__ src, uint32_t* __restrict__ st,
          uint32_t* __restrict__ eq) {
  uint32_t row = blockIdx.y;
  uint32_t thr = st[row * 8 + 2];
  uint32_t colbase = blockIdx.x * CHUNK;
  const float4* p = (const float4*)(src + (size_t)row * NN + colbase);
  for (uint32_t j = threadIdx.x; j < CHUNK / 4; j += 256) {
    float4 v = p[j];
    float vv[4] = {v.x, v.y, v.z, v.w};
#pragma unroll
    for (int e = 0; e < 4; ++e) {
      uint32_t key = (SRC == 0) ? key_x(vv[e]) : key_s(vv[e]);
      if (key == thr) {
        uint32_t idx = atomicAdd(&st[row * 8 + 5], 1u);
        if (idx < EQCAP) eq[row * EQCAP + idx] = colbase + j * 4 + e;
      }
    }
  }
}

__global__ void __launch_bounds__(256)
k_choose(uint32_t* __restrict__ st, const uint32_t* __restrict__ eq, uint32_t* __restrict__ sel) {
  int row = blockIdx.x;
  uint32_t* S = st + row * 8;
  uint32_t cnt = S[5]; if (cnt > EQCAP) cnt = EQCAP;
  uint32_t m = S[4];
  for (uint32_t a = threadIdx.x; a < cnt; a += blockDim.x) {
    uint32_t my = eq[row * EQCAP + a];
    uint32_t rank = 0;
    for (uint32_t b2 = 0; b2 < cnt; ++b2) rank += (eq[row * EQCAP + b2] < my) ? 1u : 0u;
    if (rank < m) sel[row * EQCAP + rank] = my;   // lowest-index ties win
  }
  __syncthreads();
  if (threadIdx.x == 0 && m > cnt) S[4] = cnt;
}

// s = log(probs) + gumbel, fused with stage-2 pass-0 histogram; boundary ties
// of stage 1 resolved inline via sel1 so the fused histogram is exact.
__global__ void __launch_bounds__(256)
k_compute_s(const float* __restrict__ x, float* __restrict__ out,
            const uint32_t* __restrict__ st1, const uint32_t* __restrict__ sel1,
            uint32_t* __restrict__ hist) {
  __shared__ uint32_t lh[2048];
  uint32_t row = blockIdx.y;
  for (uint32_t b = threadIdx.x; b < 2048; b += 256) lh[b] = 0u;
  __syncthreads();
  uint32_t thr1 = st1[row * 8 + 2];
  uint32_t m1 = st1[row * 8 + 4];
  float CT = c_top_val(), CR = c_rand_val();
  uint32_t colbase = blockIdx.x * CHUNK;
  const float4* px = (const float4*)(x + (size_t)row * NN + colbase);
  float4* po = (float4*)(out + (size_t)row * NN + colbase);
  for (uint32_t j = threadIdx.x; j < CHUNK / 4; j += 256) {
    float4 v = px[j];
    float vv[4] = {v.x, v.y, v.z, v.w};
    float rr[4];
#pragma unroll
    for (int e = 0; e < 4; ++e) {
      uint32_t col = colbase + j * 4 + e;
      uint32_t key = key_x(vv[e]);
      float c = CR;
      if (key > thr1) c = CT;
      else if (key == thr1) {
        for (uint32_t q = 0; q < m1; ++q)
          if (sel1[row * EQCAP + q] == col) { c = CT; break; }
      }
      float s = c + gumbel_at(row * NN + col);
      rr[e] = s;
      atomicAdd(&lh[key_s(s) >> 21], 1u);
    }
    po[j] = make_float4(rr[0], rr[1], rr[2], rr[3]);
  }
  __syncthreads();
  uint32_t* gh = hist + row * 2048;
  for (uint32_t b = threadIdx.x; b < 2048; b += 256) {
    uint32_t v = lh[b];
    if (v) atomicAdd(&gh[b], v);
  }
}

// final mask apply, stage-2 boundary ties resolved inline via sel2
__global__ void __launch_bounds__(256)
k_final(const float* __restrict__ x, float* __restrict__ out,
        const uint32_t* __restrict__ st2, const uint32_t* __restrict__ sel2) {
  uint32_t row = blockIdx.y;
  uint32_t thr2 = st2[row * 8 + 2];
  uint32_t m2 = st2[row * 8 + 4];
  uint32_t colbase = blockIdx.x * CHUNK;
  const float4* px = (const float4*)(x + (size_t)row * NN + colbase);
  float4* po = (float4*)(out + (size_t)row * NN + colbase);
  for (uint32_t j = threadIdx.x; j < CHUNK / 4; j += 256) {
    float4 sv = po[j];
    float4 xv = px[j];
    float ss[4] = {sv.x, sv.y, sv.z, sv.w};
    float xx[4] = {xv.x, xv.y, xv.z, xv.w};
    float rr[4];
#pragma unroll
    for (int e = 0; e < 4; ++e) {
      uint32_t key = key_s(ss[e]);
      float r = 0.0f;
      if (key > thr2) r = xx[e];
      else if (key == thr2) {
        for (uint32_t q = 0; q < m2; ++q)
          if (sel2[row * EQCAP + q] == colbase + j * 4 + e) { r = xx[e]; break; }
      }
      rr[e] = r;
    }
    po[j] = make_float4(rr[0], rr[1], rr[2], rr[3]);
  }
}

extern "C" void kernel_launch(void* const* d_in, const int* in_sizes, int n_in,
                              void* d_out, int out_size, void* d_ws, size_t ws_size,
                              hipStream_t stream) {
  const float* x = (const float*)d_in[0];
  float* out = (float*)d_out;

  uint32_t* w = (uint32_t*)d_ws;
  uint32_t* h0 = w;                 // 6 hist slots, 32*2048 u32 each
  uint32_t* h1 = h0 + HSLOT;
  uint32_t* h2 = h1 + HSLOT;
  uint32_t* h3 = h2 + HSLOT;        // stage-2 pass-0 (fused into compute_s)
  uint32_t* h4 = h3 + HSLOT;
  uint32_t* h5 = h4 + HSLOT;
  uint32_t* st1 = h5 + HSLOT;       // 32*8 u32
  uint32_t* st2 = st1 + 32 * 8;
  uint32_t* eq1 = st2 + 32 * 8;     // 32*EQCAP u32 each
  uint32_t* sel1 = eq1 + 32 * EQCAP;
  uint32_t* eq2 = sel1 + 32 * EQCAP;
  uint32_t* sel2 = eq2 + 32 * EQCAP;

  dim3 blk(256), gridH(W, BB), gridR(BB);

  hipMemsetAsync(w, 0, MEMSET_BYTES, stream);   // all hists + st1 + st2

  // ---- stage 1: radix select on key_x(|x|), 11+11+10 bits ----
  k_hist<0><<<gridH, blk, 0, stream>>>(x, h0, st1, 0);
  k_scan<<<gridR, blk, 0, stream>>>(h0, st1, 0);
  k_hist<0><<<gridH, blk, 0, stream>>>(x, h1, st1, 1);
  k_scan<<<gridR, blk, 0, stream>>>(h1, st1, 1);
  k_hist<0><<<gridH, blk, 0, stream>>>(x, h2, st1, 2);
  k_scan<<<gridR, blk, 0, stream>>>(h2, st1, 2);
  k_collect<0><<<gridH, blk, 0, stream>>>(x, st1, eq1);
  k_choose<<<gridR, blk, 0, stream>>>(st1, eq1, sel1);

  // ---- s = log(probs)+gumbel (ties inline), fused stage-2 pass-0 hist ----
  k_compute_s<<<gridH, blk, 0, stream>>>(x, out, st1, sel1, h3);

  // ---- stage 2: radix select on key_s(s) ----
  k_scan<<<gridR, blk, 0, stream>>>(h3, st2, 0);
  k_hist<1><<<gridH, blk, 0, stream>>>(out, h4, st2, 1);
  k_scan<<<gridR, blk, 0, stream>>>(h4, st2, 1);
  k_hist<1><<<gridH, blk, 0, stream>>>(out, h5, st2, 2);
  k_scan<<<gridR, blk, 0, stream>>>(h5, st2, 2);
  k_collect<1><<<gridH, blk, 0, stream>>>(out, st2, eq2);
  k_choose<<<gridR, blk, 0, stream>>>(st2, eq2, sel2);

  // ---- apply mask (ties inline) ----
  k_final<<<gridH, blk, 0, stream>>>(x, out, st2, sel2);
}